// Round 8
// baseline (166.250 us; speedup 1.0000x reference)
//
#include <hip/hip_runtime.h>
#include <math.h>

#define CIN    64
#define OUTC   64
#define BOT    16
#define KK     9
#define HH     48
#define WW     48
#define LPIX   (HH*WW)
#define WSZ    9216
#define PSZ    1024
#define PREDCH 10304
#define GRPSZ  2576
#define BATCH  2
#define NPX    9           // 3x3 pixel tile per block
#define PXS2   1172        // px-stride (ushorts): c-stride 18 (16 d + 2 pad), 64c + 20
#define XTS    25          // xt per-c stride (floats): 5x5 spatial window
#define DBS    65

typedef __attribute__((ext_vector_type(8))) short short8v;
typedef __attribute__((ext_vector_type(4))) float float4v;

__device__ inline unsigned short f2bf(float f){
    unsigned u = __float_as_uint(f);
    return (unsigned short)((u + 0x7FFFu + ((u>>16)&1u)) >> 16);   // RNE
}

__global__ __launch_bounds__(256) void cvt_wp(const float* __restrict__ Wp,
                                              unsigned short* __restrict__ Wb) {
    const int n = PREDCH * 16;
    for (int i = blockIdx.x * 256 + threadIdx.x; i < n; i += gridDim.x * 256)
        Wb[i] = f2bf(Wp[i]);
}

// Block = 9 px (3x3), grid 512 (~2/CU, LDS ~51 KB -> 2-3 blocks resident). 576 threads.
// Same verified structure as dppc7; only geometry changed so blocks co-schedule
// (pred VALU/VMEM of one block overlaps Y MFMA/LDS of another).
__global__ __launch_bounds__(576, 6) void dppc8(
    const float* __restrict__ x,
    const unsigned short* __restrict__ Wb,
    const float* __restrict__ bp,
    float* __restrict__ out)
{
    __shared__ float          xt[64 * XTS];         //  6400 B  [c][r5][c5]
    __shared__ unsigned short S[2][NPX * PXS2];     // 42192 B  P_t dbuf; S[0] also stages Q
    __shared__ float          dynb[NPX * DBS];      //  2340 B

    const int tid  = threadIdx.x;
    const int wave = tid >> 6;
    const int lane = tid & 63;
    const int quad = lane >> 4;
    const int lrow = lane & 15;

    const int bi = blockIdx.x;
    const int b  = bi >> 8;            // 256 tiles per image
    const int r  = bi & 255;
    const int h0 = (r >> 4) * 3;
    const int w0 = (r & 15) * 3;

    // ---- xt load: rows h0-1..h0+3, cols w0-1..w0+3, zero-padded ----
    const float* xb = x + (size_t)b * CIN * LPIX;
    for (int i = tid; i < 64 * XTS; i += 576) {
        const int c  = i / XTS;
        const int rm = i - c * XTS;
        const int hi = h0 - 1 + rm / 5;
        const int wi = w0 - 1 + rm % 5;
        float v = 0.0f;
        if (hi >= 0 && hi < HH && wi >= 0 && wi < WW)
            v = xb[c * LPIX + hi * WW + wi];
        xt[i] = v;
    }
    __syncthreads();

    // ---- pred B-frag from center x (t-independent); n = lrow = px ----
    short8v Bf[4];
    #pragma unroll
    for (int g = 0; g < 4; ++g) {
        const int px = lrow;
        short8v f = (short8v)0;
        if (quad < 2 && px < NPX) {
            const int pr = px / 3, pc = px - 3 * (px / 3);
            #pragma unroll
            for (int j = 0; j < 8; ++j)
                f[j] = (short)f2bf(xt[(g * 16 + quad * 8 + j) * XTS + (pr + 1) * 5 + pc + 1]);
        }
        if (quad == 2 && lrow < NPX) f[0] = (short)0x3F80;   // bf16(1.0) bias slot
        Bf[g] = f;
    }

    // ---- Q + dyn_b phase (group 3), Q -> S[0] as [px][o*18+d] ----
    for (int u = wave; u < 68; u += 9) {
        const int ch0  = WSZ + u * 16;
        const int mych = ch0 + lrow;
        short8v a = (short8v)0;
        if (quad < 2)       a = *(const short8v*)(Wb + (size_t)mych * 16 + quad * 8);
        else if (quad == 2) a[0] = (short)f2bf(bp[mych]);
        float4v Dv = {0.f, 0.f, 0.f, 0.f};
        Dv = __builtin_amdgcn_mfma_f32_16x16x32_bf16(a, Bf[3], Dv, 0, 0, 0);
        const int px = lrow;
        if (px < NPX) {
            #pragma unroll
            for (int rr = 0; rr < 4; ++rr) {
                const int ch = ch0 + quad * 4 + rr;
                if (ch < WSZ + PSZ) {
                    const int i = ch - WSZ;
                    S[0][px * PXS2 + (i >> 4) * 18 + (i & 15)] = f2bf(Dv[rr]);
                } else {
                    dynb[px * DBS + (ch - WSZ - PSZ)] = Dv[rr];
                }
            }
        }
    }
    __syncthreads();

    // ---- cache Q B-frags in registers: this wave's pixel (px = wave) ----
    const int pxA = wave;              // 0..8
    short8v Bq[4];
    #pragma unroll
    for (int Nt = 0; Nt < 4; ++Nt) {
        short8v f = (short8v)0;
        if (quad < 2)
            f = *(const short8v*)&S[0][pxA * PXS2 + (Nt * 16 + lrow) * 18 + quad * 8];
        Bq[Nt] = f;
    }
    __syncthreads();   // all waves done reading S[0] before pred(0) overwrites it

    float acc[4] = {};

    // ---- pred slice for tap t into buf (STATIC Bf indices) ----
    #define PASS(GG)                                                                  \
        { short8v am = (myg == (GG)) ? a : (short8v)0;                                \
          Dv = __builtin_amdgcn_mfma_f32_16x16x32_bf16(am, Bf[GG], Dv, 0, 0, 0); }

    #define PRED_SLICE(T, BUF)                                                        \
    for (int u = wave; u < 64; u += 9) {                                              \
        const int d  = u >> 2;                                                        \
        const int c0 = (u & 3) * 16;                                                  \
        const int ch0  = d * 576 + c0 * 9 + (T);                                      \
        const int mych = ch0 + 9 * lrow;                                              \
        short8v a = (short8v)0;                                                       \
        if (quad < 2)       a = *(const short8v*)(Wb + (size_t)mych * 16 + quad * 8); \
        else if (quad == 2) a[0] = (short)f2bf(bp[mych]);                             \
        const int g0  = ch0 / GRPSZ;                                                  \
        const int g1  = (ch0 + 135) / GRPSZ;                                          \
        const int myg = mych / GRPSZ;                                                 \
        float4v Dv = {0.f, 0.f, 0.f, 0.f};                                            \
        if (g0 == 0)      { PASS(0) if (g1 == 1) PASS(1) }                            \
        else if (g0 == 1) { PASS(1) if (g1 == 2) PASS(2) }                            \
        else if (g0 == 2) { PASS(2) if (g1 == 3) PASS(3) }                            \
        else              { PASS(3) }                                                 \
        const int px = lrow;                                                          \
        if (px < NPX) {                                                               \
            _Pragma("unroll")                                                         \
            for (int rr = 0; rr < 4; ++rr)                                            \
                S[BUF][px * PXS2 + (c0 + quad * 4 + rr) * 18 + d] = f2bf(Dv[rr]);     \
        }                                                                             \
    }

    PRED_SLICE(0, 0)
    __syncthreads();

    for (int t = 0; t < KK; ++t) {
        const int buf = t & 1;
        if (t < 8) { PRED_SLICE(t + 1, (t + 1) & 1) }

        // ---- Y = P_t^T Q for this wave's pixel ----
        const int tr = t / 3, tc = t - 3 * (t / 3);
        const int pr = pxA / 3, pc = pxA - 3 * (pxA / 3);

        short8v Ap[4];
        #pragma unroll
        for (int Mt = 0; Mt < 4; ++Mt) {
            short8v f = (short8v)0;
            if (quad < 2)
                f = *(const short8v*)&S[buf][pxA * PXS2 + (Mt * 16 + lrow) * 18 + quad * 8];
            Ap[Mt] = f;
        }
        float pv[4][4];
        #pragma unroll
        for (int Mt = 0; Mt < 4; ++Mt)
            #pragma unroll
            for (int rr = 0; rr < 4; ++rr) {
                const int c = Mt * 16 + quad * 4 + rr;
                pv[Mt][rr] = xt[c * XTS + (pr + tr) * 5 + pc + tc];
            }

        #pragma unroll
        for (int Nt = 0; Nt < 4; ++Nt) {
            float nacc = 0.f, dpacc = 0.f;
            #pragma unroll
            for (int Mt = 0; Mt < 4; ++Mt) {
                float4v Dv = {0.f, 0.f, 0.f, 0.f};
                Dv = __builtin_amdgcn_mfma_f32_16x16x32_bf16(Ap[Mt], Bq[Nt], Dv, 0, 0, 0);
                #pragma unroll
                for (int rr = 0; rr < 4; ++rr) {
                    nacc  += Dv[rr] * Dv[rr];
                    dpacc += pv[Mt][rr] * Dv[rr];
                }
            }
            nacc  += __shfl_xor(nacc, 16);  nacc  += __shfl_xor(nacc, 32);
            dpacc += __shfl_xor(dpacc, 16); dpacc += __shfl_xor(dpacc, 32);
            acc[Nt] += dpacc / fmaxf(sqrtf(fmaxf(nacc, 0.f)), 1e-12f);
        }
        __syncthreads();
    }

    // ---- write out ----
    if (quad == 0) {
        const int pr = pxA / 3, pc = pxA - 3 * (pxA / 3);
        const int l  = (h0 + pr) * WW + (w0 + pc);
        #pragma unroll
        for (int Nt = 0; Nt < 4; ++Nt) {
            const int o = Nt * 16 + lrow;
            out[((size_t)b * OUTC + o) * LPIX + l] = acc[Nt] + dynb[pxA * DBS + o];
        }
    }
}

extern "C" void kernel_launch(void* const* d_in, const int* in_sizes, int n_in,
                              void* d_out, int out_size, void* d_ws, size_t ws_size,
                              hipStream_t stream) {
    const float* x  = (const float*)d_in[0];
    const float* Wp = (const float*)d_in[1];
    const float* bp = (const float*)d_in[2];
    float* out = (float*)d_out;
    unsigned short* Wb = (unsigned short*)d_ws;   // PREDCH*16 bf16 = 330 KB
    (void)in_sizes; (void)n_in; (void)out_size; (void)ws_size;

    hipLaunchKernelGGL(cvt_wp, dim3(160), dim3(256), 0, stream, Wp, Wb);
    hipLaunchKernelGGL(dppc8, dim3(BATCH * 256), dim3(576), 0, stream, x, Wb, bp, out);
}